// Round 12
// baseline (5208.103 us; speedup 1.0000x reference)
//
#include <hip/hip_runtime.h>
#include <hip/hip_bf16.h>
#include <math.h>

#define V_  128
#define E_  512
#define H_  1024
#define NE_ 10
#define B_  32
#define S_  1024
#define G4H (4*H_)   // 4096

typedef short bf16x8 __attribute__((ext_vector_type(8)));
typedef float f32x4  __attribute__((ext_vector_type(4)));
typedef int   i32x4  __attribute__((ext_vector_type(4)));

__device__ __forceinline__ short f2bf(float f) {
    __hip_bfloat16 h = __float2bfloat16(f);
    short s; __builtin_memcpy(&s, &h, 2); return s;
}
__device__ __forceinline__ float bf2f(ushort u) {
    unsigned int x = ((unsigned int)u) << 16;
    float f; __builtin_memcpy(&f, &x, 4); return f;
}
__device__ __forceinline__ float sigf(float x) { return 1.f / (1.f + __expf(-x)); }
__device__ __forceinline__ float tanhfast(float x) { return 1.f - 2.f / (__expf(2.f * x) + 1.f); }

// ---- agent-scope (sc1) coherent ops — R10/R11-verified cross-XCD at the IC ----
__device__ __forceinline__ i32x4 gload4_sc(const void* p) {
    i32x4 r;
    asm volatile("global_load_dwordx4 %0, %1, off sc1" : "=&v"(r) : "v"(p));
    return r;
}
__device__ __forceinline__ void gstore4_sc(void* p, i32x4 v) {
    asm volatile("global_store_dwordx4 %0, %1, off sc1" :: "v"(p), "v"(v) : "memory");
}
__device__ __forceinline__ void gstore1_sc(void* p, int v) {
    asm volatile("global_store_dword %0, %1, off sc1" :: "v"(p), "v"(v) : "memory");
}
// wait for loads AND pin the compiler (rule #18)
#define WAITCNT0() do { asm volatile("s_waitcnt vmcnt(0)" ::: "memory"); \
                        __builtin_amdgcn_sched_barrier(0); } while (0)

// ---------------- K1: T2[v][j*4+q] = emb[v] . W_ih[q*H+j] + b_ih[q*H+j] ----------------
__global__ __launch_bounds__(256) void build_T(
    const float* __restrict__ emb, const float* __restrict__ W_ih,
    const float* __restrict__ b_ih, float* __restrict__ T2)
{
    int idx = blockIdx.x * 256 + threadIdx.x;    // over 4096*128
    int g = idx >> 7, v = idx & 127;
    const float* er = emb + v * E_;
    const float* wr = W_ih + (size_t)g * E_;
    float acc = b_ih[g];
    #pragma unroll 4
    for (int e = 0; e < E_; ++e) acc += er[e] * wr[e];
    T2[v * G4H + (g & 1023) * 4 + (g >> 10)] = acc;   // [v][j][q] layout
}

// ---------------- K1b: We -> bf16 ----------------
__global__ __launch_bounds__(256) void conv_bf16(
    const float* __restrict__ src, ushort* __restrict__ dst, int n)
{
    int i = blockIdx.x * 256 + threadIdx.x;
    if (i < n) dst[i] = (ushort)f2bf(src[i]);
}

// ---------------- K2: persistent LSTM scan, 128 blocks x 512 thr ----------------
// R11 structure; R12 changes: (1) fragment-major Wl layout -> lane-linear
// ds_read_b128 (zero bank conflicts), (2) linear preF/padded part layouts,
// (3) only bh=0 waves poll flags (partner waits on LDS epoch), (4) x/T2
// prefetched right after readiness gate.
__global__ __launch_bounds__(512) void lstm_scan(
    const int* __restrict__ x, const float* __restrict__ T2,
    const float* __restrict__ W_hh, const float* __restrict__ b_hh,
    ushort* __restrict__ hbuf, ushort* __restrict__ h_all, int* __restrict__ flags)
{
    const int p = blockIdx.x;            // 0..127
    const int tid = threadIdx.x;         // 0..511
    const int lane = tid & 63, wave = tid >> 6;
    const int m = lane & 15, kg = lane >> 4;
    const int bh = wave & 1, kq = wave >> 1;   // batch-half, K-quarter

    __shared__ __align__(16) ushort Wl[32768];       // 64KB fragment-major W slice
    __shared__ float  part[8 * 544];                 // padded wave partials (17KB)
    __shared__ __align__(16) float preF[1024];       // pre-acts, addr = b*32 + r
    __shared__ __align__(16) ushort hstage[256];
    __shared__ float  bhh_l[32];
    __shared__ int    eps4[4];

    // ---- stage W slice to LDS (once), fragment-major:
    // frag(tile,kq,kk,kg) slot holds 16 lanes' (m) bf16x8 at k = kq*256+kk*32+kg*8
    #pragma unroll
    for (int i = 0; i < 8; ++i) {
        int grp = tid + i * 512;             // 0..4095
        int r = grp >> 7, kglob = grp & 127;
        int k8 = kglob * 8;
        const float* wsrc = W_hh + (size_t)((r & 3) * H_ + p * 8 + (r >> 2)) * H_ + k8;
        float4 w0 = *(const float4*)wsrc;
        float4 w1 = *(const float4*)(wsrc + 4);
        bf16x8 a;
        a[0]=f2bf(w0.x); a[1]=f2bf(w0.y); a[2]=f2bf(w0.z); a[3]=f2bf(w0.w);
        a[4]=f2bf(w1.x); a[5]=f2bf(w1.y); a[6]=f2bf(w1.z); a[7]=f2bf(w1.w);
        int tile = r >> 4, mm = r & 15;
        int kq2 = kglob >> 5, kk = (kglob >> 2) & 7, kg2 = kglob & 3;
        int frag = ((tile * 4 + kq2) * 8 + kk) * 4 + kg2;       // 0..255
        *(bf16x8*)&Wl[(frag * 16 + mm) * 8] = a;
    }
    if (tid < 32) bhh_l[tid] = b_hh[(tid & 3) * H_ + p * 8 + (tid >> 2)];
    if (tid < 4)  eps4[tid] = 0;

    // B-chunk offsets (ushorts): each 16B chunk == one producer's 16B store
    int boff[8];
    #pragma unroll
    for (int kk = 0; kk < 8; ++kk)
        boff[kk] = (bh * 16 + m) * 1024 + kq * 256 + kk * 32 + kg * 8;

    const int eb = tid >> 3, eu = tid & 7;   // epilogue mapping (tid<256)
    float cst = 0.f;
    ushort* hb0 = hbuf;
    ushort* hb1 = hbuf + B_ * H_;
    __syncthreads();

    for (int t = 0; t < S_; ++t) {
        const ushort* hrd = (t & 1) ? hb0 : hb1;   // h_{t-1}; t=0 -> zeroed hb1
        ushort*       hwr = (t & 1) ? hb1 : hb0;

        // ---- readiness gate: bh=0 wave polls its K-quarter's 32 source flags;
        //      bh=1 partner waits on the LDS epoch ----
        if (bh == 0) {
            const int src = kq * 32 + (lane & 31);
            const int* fp = flags + src * 16;
            for (;;) {
                int f;
                asm volatile("global_load_dword %0, %1, off sc1\n\ts_waitcnt vmcnt(0)"
                             : "=&v"(f) : "v"(fp) : "memory");
                __builtin_amdgcn_sched_barrier(0);
                if (__all(f >= t)) break;
                __builtin_amdgcn_s_sleep(1);
            }
            __hip_atomic_store(&eps4[kq], t, __ATOMIC_RELEASE, __HIP_MEMORY_SCOPE_WORKGROUP);
        } else {
            while (__hip_atomic_load(&eps4[kq], __ATOMIC_ACQUIRE, __HIP_MEMORY_SCOPE_WORKGROUP) < t)
                __builtin_amdgcn_s_sleep(1);
        }

        // ---- prefetch gate-table rows (normal cached loads; hide under MFMA) ----
        int xv = 0; float4 tv = {0.f, 0.f, 0.f, 0.f};
        if (tid < 256) {
            xv = x[eb * S_ + t];
            tv = *(const float4*)(T2 + (size_t)xv * G4H + (size_t)(p * 8 + eu) * 4);
        }

        // ---- load my 8 disjoint B-chunks from the coherence point ----
        i32x4 braw[8];
        #pragma unroll
        for (int kk = 0; kk < 8; ++kk) braw[kk] = gload4_sc(hrd + boff[kk]);
        WAITCNT0();

        // ---- MFMA: 2 row-tiles x 8 kk; A-reads are lane-linear (conflict-free) ----
        f32x4 acc0 = {0.f,0.f,0.f,0.f}, acc1 = {0.f,0.f,0.f,0.f};
        #pragma unroll
        for (int kk = 0; kk < 8; ++kk) {
            int f0 = ((0 * 4 + kq) * 8 + kk) * 4 + kg;   // tile0 frag
            int f1 = ((1 * 4 + kq) * 8 + kk) * 4 + kg;   // tile1 frag
            bf16x8 a0 = *(const bf16x8*)&Wl[(f0 * 16 + m) * 8];
            bf16x8 a1 = *(const bf16x8*)&Wl[(f1 * 16 + m) * 8];
            bf16x8 bv; __builtin_memcpy(&bv, &braw[kk], 16);
            acc0 = __builtin_amdgcn_mfma_f32_16x16x32_bf16(a0, bv, acc0, 0, 0, 0);
            acc1 = __builtin_amdgcn_mfma_f32_16x16x32_bf16(a1, bv, acc1, 0, 0, 0);
        }
        // D: row16 = kg*4+d, col(batch) = m; padded stride 17
        {
            float* pw = part + wave * 544;
            #pragma unroll
            for (int d = 0; d < 4; ++d) {
                pw[(kg * 4 + d) * 17 + m]       = acc0[d];
                pw[272 + (kg * 4 + d) * 17 + m] = acc1[d];
            }
        }
        __syncthreads();

        // ---- reduce over kq -> preF[b*32 + r] (write lane-linear) ----
        #pragma unroll
        for (int i = 0; i < 2; ++i) {
            int flat = tid + i * 512;            // 0..1023
            int b = flat & 31, r = flat >> 5;
            int bh2 = b >> 4, mm = b & 15, tile = r >> 4, row16 = r & 15;
            int off = tile * 272 + row16 * 17 + mm;
            float s = part[(0 * 2 + bh2) * 544 + off] + part[(1 * 2 + bh2) * 544 + off]
                    + part[(2 * 2 + bh2) * 544 + off] + part[(3 * 2 + bh2) * 544 + off];
            preF[b * 32 + r] = s;
        }
        __syncthreads();

        // ---- epilogue: thread = (batch eb, unit eu); preF read is tid-linear ----
        if (tid < 256) {
            float4 pv = *(const float4*)&preF[tid * 4];   // gates i,f,g,o of (eb,eu)
            int r0 = eu * 4;
            float pi = pv.x + tv.x + bhh_l[r0 + 0];
            float pf = pv.y + tv.y + bhh_l[r0 + 1];
            float pg = pv.z + tv.z + bhh_l[r0 + 2];
            float po = pv.w + tv.w + bhh_l[r0 + 3];
            cst = sigf(pf) * cst + sigf(pi) * tanhfast(pg);
            float h = sigf(po) * tanhfast(cst);
            unsigned int hb16 = (unsigned int)(unsigned short)f2bf(h);
            unsigned int hn = (unsigned int)__shfl_xor((int)hb16, 1);
            if (!(eu & 1))
                *(unsigned int*)(h_all + (size_t)eb * (S_ * H_) + (size_t)t * H_ + (p * 8 + eu))
                    = hb16 | (hn << 16);
            hstage[tid] = (ushort)hb16;        // hstage[eb*8+eu]
        }
        __syncthreads();                       // hstage complete

        if (t == S_ - 1) break;

        // ---- publish 512B + flag (wave0); others run ahead to next poll ----
        if (wave == 0) {
            if (lane < 32) {
                i32x4 v = *(const i32x4*)&hstage[lane * 8];
                gstore4_sc(hwr + lane * 1024 + p * 8, v);   // 16B = this block's 8 units
            }
            asm volatile("s_waitcnt vmcnt(0)" ::: "memory"); // h_t at coherence point
            if (lane == 0) gstore1_sc(flags + p * 16, t + 1);
        }
    }
}

// ---------------- K3: expert GEMM (bf16 MFMA)  C = A . Bw^T + be ----------------
__global__ __launch_bounds__(256) void expert_gemm(
    const ushort* __restrict__ A, const ushort* __restrict__ Bw,
    const float* __restrict__ be, float* __restrict__ out)
{
    __shared__ ushort As[128][40];
    __shared__ ushort Bs[128][40];
    const int tid = threadIdx.x;
    const int bm = blockIdx.x / 10, bn = blockIdx.x % 10;
    const int m0 = bm * 128, n0 = bn * 128;
    const int lane = tid & 63, wave = tid >> 6;
    const int wm = wave >> 1, wn = wave & 1;
    const int fm = lane & 15, kg = lane >> 4;

    const int srow = tid >> 1, scol = (tid & 1) * 16;
    const ushort* Ag = A  + (size_t)(m0 + srow) * H_ + scol;
    const ushort* Bg = Bw + (size_t)(n0 + srow) * H_ + scol;

    f32x4 acc[4][4];
    #pragma unroll
    for (int i = 0; i < 4; ++i)
        #pragma unroll
        for (int j = 0; j < 4; ++j) acc[i][j] = (f32x4){0.f,0.f,0.f,0.f};

    int4 ra0 = *(const int4*)(Ag),     ra1 = *(const int4*)(Ag + 8);
    int4 rb0 = *(const int4*)(Bg),     rb1 = *(const int4*)(Bg + 8);

    for (int k0 = 0; k0 < H_; k0 += 32) {
        __syncthreads();
        *(int4*)&As[srow][scol] = ra0;  *(int4*)&As[srow][scol + 8] = ra1;
        *(int4*)&Bs[srow][scol] = rb0;  *(int4*)&Bs[srow][scol + 8] = rb1;
        __syncthreads();
        if (k0 + 32 < H_) {
            ra0 = *(const int4*)(Ag + k0 + 32);  ra1 = *(const int4*)(Ag + k0 + 40);
            rb0 = *(const int4*)(Bg + k0 + 32);  rb1 = *(const int4*)(Bg + k0 + 40);
        }
        bf16x8 af[4], bfv[4];
        #pragma unroll
        for (int i = 0; i < 4; ++i) af[i] = *(const bf16x8*)&As[wm * 64 + i * 16 + fm][kg * 8];
        #pragma unroll
        for (int j = 0; j < 4; ++j) bfv[j] = *(const bf16x8*)&Bs[wn * 64 + j * 16 + fm][kg * 8];
        #pragma unroll
        for (int i = 0; i < 4; ++i)
            #pragma unroll
            for (int j = 0; j < 4; ++j)
                acc[i][j] = __builtin_amdgcn_mfma_f32_16x16x32_bf16(af[i], bfv[j], acc[i][j], 0, 0, 0);
    }

    const int e = bn;
    const size_t ebase = (size_t)e * ((size_t)B_ * S_ * V_);
    #pragma unroll
    for (int i = 0; i < 4; ++i) {
        #pragma unroll
        for (int d = 0; d < 4; ++d) {
            int row = m0 + wm * 64 + i * 16 + kg * 4 + d;
            float* orow = out + ebase + (size_t)row * V_;
            #pragma unroll
            for (int j = 0; j < 4; ++j) {
                int col = wn * 64 + j * 16 + fm;
                orow[col] = acc[i][j][d] + be[n0 + col];
            }
        }
    }
}

// ---------------- K4: gating softmax (bf16 h) ----------------
__global__ __launch_bounds__(256) void gating_kernel(
    const ushort* __restrict__ h_all, const float* __restrict__ Wg,
    const float* __restrict__ bg, float* __restrict__ gate_out)
{
    int b = blockIdx.x;
    int tid = threadIdx.x;
    __shared__ float red[NE_][256];
    const ushort* h = h_all + (size_t)b * (S_ * H_) + (size_t)(S_ - 1) * H_;
    float pa[NE_];
    #pragma unroll
    for (int e = 0; e < NE_; ++e) pa[e] = 0.f;
    for (int k = tid; k < H_; k += 256) {
        float hv = bf2f(h[k]);
        #pragma unroll
        for (int e = 0; e < NE_; ++e) pa[e] += hv * Wg[e * H_ + k];
    }
    #pragma unroll
    for (int e = 0; e < NE_; ++e) red[e][tid] = pa[e];
    __syncthreads();
    for (int s = 128; s > 0; s >>= 1) {
        if (tid < s) {
            #pragma unroll
            for (int e = 0; e < NE_; ++e) red[e][tid] += red[e][tid + s];
        }
        __syncthreads();
    }
    if (tid == 0) {
        float lg[NE_], mx = -1e30f;
        #pragma unroll
        for (int e = 0; e < NE_; ++e) { lg[e] = red[e][0] + bg[e]; mx = fmaxf(mx, lg[e]); }
        float s = 0.f;
        #pragma unroll
        for (int e = 0; e < NE_; ++e) { lg[e] = expf(lg[e] - mx); s += lg[e]; }
        #pragma unroll
        for (int e = 0; e < NE_; ++e) gate_out[b * NE_ + e] = lg[e] / s;
    }
}

// ---------------- K5: combine ----------------
__global__ __launch_bounds__(256) void combine_kernel(
    const float* __restrict__ exp_out, const float* __restrict__ gate,
    float* __restrict__ comb)
{
    int idx = blockIdx.x * 256 + threadIdx.x;  // < 4194304
    int b = idx >> 17;
    float acc = 0.f;
    #pragma unroll
    for (int e = 0; e < NE_; ++e)
        acc += gate[b * NE_ + e] * exp_out[(size_t)e * (size_t)(B_ * S_ * V_) + idx];
    comb[idx] = acc;
}

extern "C" void kernel_launch(void* const* d_in, const int* in_sizes, int n_in,
                              void* d_out, int out_size, void* d_ws, size_t ws_size,
                              hipStream_t stream)
{
    const int*   x    = (const int*)  d_in[0];
    const float* emb  = (const float*)d_in[1];
    const float* W_ih = (const float*)d_in[2];
    const float* W_hh = (const float*)d_in[3];
    const float* b_ih = (const float*)d_in[4];
    const float* b_hh = (const float*)d_in[5];
    const float* We   = (const float*)d_in[6];
    const float* be   = (const float*)d_in[7];
    const float* Wg   = (const float*)d_in[8];
    const float* bg   = (const float*)d_in[9];

    float* out     = (float*)d_out;
    float* comb    = out;                               // [B,S,V]
    float* exp_out = out + 4194304;                     // [NE,B,S,V]
    float* gate    = out + 4194304 + 41943040;          // [B,NE]

    char*   ws    = (char*)d_ws;
    float*  T2    = (float*)ws;                               // 2 MB
    ushort* hbuf  = (ushort*)(ws + (2u << 20));               // 2 x 64 KB bf16
    int*    flags = (int*)   (ws + (2u << 20) + (128u << 10));// 128 x 64B slots = 8 KB
    ushort* We_bf = (ushort*)(ws + (4u << 20));               // 2.6 MB
    ushort* h_all = (ushort*)(ws + (8u << 20));               // 67 MB [B,S,H] bf16

    // zero h double-buffer (h0 = 0) and flags — required every replay
    (void)hipMemsetAsync(ws + (2u << 20), 0, (136u << 10), stream);

    build_T      <<<2048, 256, 0, stream>>>(emb, W_ih, b_ih, T2);
    conv_bf16    <<<(NE_ * V_ * H_ + 255) / 256, 256, 0, stream>>>(We, We_bf, NE_ * V_ * H_);
    lstm_scan    <<<128, 512, 0, stream>>>(x, T2, W_hh, b_hh, hbuf, h_all, flags);
    expert_gemm  <<<256 * 10, 256, 0, stream>>>(h_all, We_bf, be, exp_out);
    gating_kernel<<<B_, 256, 0, stream>>>(h_all, Wg, bg, gate);
    combine_kernel<<<4194304 / 256, 256, 0, stream>>>(exp_out, gate, comb);
}